// Round 3
// baseline (27275.751 us; speedup 1.0000x reference)
//
#include <hip/hip_runtime.h>
#include <hip/hip_bf16.h>

// CriticRDDPG forward: B=128, T=512, A=256, U_GRU=512
// ALL inputs/outputs are FLOAT32 (per reference). bf16 used only internally
// as MFMA operands. d_out: [out(128) | h_final(128*512)] f32.
// T processed in 16 chunks of CH=32 steps; ws usage ~34.3 MiB.

using bf16 = __hip_bfloat16;
typedef __bf16 bf16x8 __attribute__((ext_vector_type(8)));
typedef float f32x4 __attribute__((ext_vector_type(4)));

#define CH 32
#define NCHUNK 16

__device__ __forceinline__ bf16 f2bf(float f) { return __float2bfloat16(f); }
__device__ __forceinline__ float sigm(float x) { return 1.f / (1.f + __expf(-x)); }
__device__ __forceinline__ float tanh_(float x) {
  float ax = fabsf(x);
  float t = __expf(-2.f * ax);
  float r = (1.f - t) / (1.f + t);
  return copysignf(r, x);
}
__device__ __forceinline__ float elu_(float x) { return x > 0.f ? x : __expf(x) - 1.f; }
__device__ __forceinline__ f32x4 mfma16(bf16x8 a, bf16x8 b, f32x4 c) {
  return __builtin_amdgcn_mfma_f32_16x16x32_bf16(a, b, c, 0, 0, 0);
}

// -------------------- workspace layout (bytes) --------------------
#define OFF_H   0ul                     // h state f32 [128][512]          =   262144
#define OFF_HM  262144ul                // hmax f32 [128][512]             =   262144
#define OFF_PRK 524288ul                // packed gru_rk bf16              =  1572864
#define OFF_PGK 2097152ul               // packed gru_k bf16               =  2359296
#define OFF_X   4456448ul               // x chunk bf16 [128*CH][768]      =  6291456
#define OFF_XP  10747904ul              // x_proj chunk f32 [CH][128][1536]= 25165824
// total = 35913728 (~34.3 MiB)

// -------------------- kernel 1: h0 --------------------
__global__ __launch_bounds__(512) void prep_h0(
    const float* __restrict__ mot, const float* __restrict__ rob,
    const float* __restrict__ state,
    const float* __restrict__ Wmot, const float* __restrict__ bmot,
    const float* __restrict__ Wrob, const float* __restrict__ brob,
    const float* __restrict__ Wcomb, const float* __restrict__ bcomb,
    float* __restrict__ h) {
  __shared__ float inbuf[128];
  __shared__ float msrs[512];
  __shared__ float st[512];
  const int tid = threadIdx.x;
  const int b = blockIdx.x;
  if (tid < 64) inbuf[tid] = mot[b * 64 + tid];
  else if (tid < 128) inbuf[tid] = rob[b * 64 + tid - 64];
  st[tid] = state[b * 512 + tid];
  __syncthreads();
  {
    float acc;
    if (tid < 256) {
      acc = bmot[tid];
      for (int k = 0; k < 64; ++k) acc += inbuf[k] * Wmot[k * 256 + tid];
    } else {
      int jj = tid - 256;
      acc = brob[jj];
      for (int k = 0; k < 64; ++k) acc += inbuf[64 + k] * Wrob[k * 256 + jj];
    }
    msrs[tid] = elu_(acc);
  }
  __syncthreads();
  float acc = bcomb[tid];
  for (int k = 0; k < 512; ++k) acc += msrs[k] * Wcomb[(size_t)k * 512 + tid];
  for (int k = 0; k < 512; ++k) acc += st[k] * Wcomb[(size_t)(512 + k) * 512 + tid];
  h[b * 512 + tid] = elu_(acc);
}

// ---------- kernel 2: pack gru_rk (f32) into MFMA B-fragment order (bf16) ----
// prk frag (nf,kf), lane l, elem e  <-  rk[k][n], n = nf*16+(l&15), k = kf*32+(l>>4)*8+e
__global__ void pack_rk(const float* __restrict__ rk, bf16* __restrict__ prk) {
  int idx = blockIdx.x * 256 + threadIdx.x;  // 96 nf * 16 kf * 64 lanes = 98304
  int nf = idx >> 10, rem = idx & 1023;
  int kf = rem >> 6, l = rem & 63;
  int n = nf * 16 + (l & 15);
  int k0 = kf * 32 + (l >> 4) * 8;
  bf16x8 v;
#pragma unroll
  for (int e = 0; e < 8; ++e)
    v[e] = (__bf16)f2bf(rk[(size_t)(k0 + e) * 1536 + n]);
  *reinterpret_cast<bf16x8*>(prk + (size_t)idx * 8) = v;
}

// ---------- kernel 3: pack gru_k (f32) into k-octet bf16 layout ----------
// pgk[(kblk*1536+n)*8 + e] = gk[kblk*8+e][n]
__global__ void pack_gk(const float* __restrict__ gk, bf16* __restrict__ pgk) {
  int idx = blockIdx.x * 256 + threadIdx.x;  // 96*1536 = 147456
  int kblk = idx / 1536, n = idx % 1536;
  bf16x8 v;
#pragma unroll
  for (int e = 0; e < 8; ++e)
    v[e] = (__bf16)f2bf(gk[(size_t)(kblk * 8 + e) * 1536 + n]);
  *reinterpret_cast<bf16x8*>(pgk + (size_t)idx * 8) = v;
}

// -------------------- kernel 4: build x chunk --------------------
// x rows: rloc = b*CH + (t - t0); cols [act(256) | inp2(256) | inp3(256)], bf16
__global__ __launch_bounds__(256) void build_x(
    const float* __restrict__ action, const float* __restrict__ osc,
    const float* __restrict__ mu, const float* __restrict__ mean,
    const float* __restrict__ Woscr, const float* __restrict__ boscr,
    const float* __restrict__ Wosci, const float* __restrict__ bosci,
    bf16* __restrict__ xw, int t0) {
  __shared__ float osc64[16][64];
  __shared__ float inp2s[16][256];
  const int j = threadIdx.x;
  const int b = blockIdx.x >> 1, tb = blockIdx.x & 1;  // CH/16 = 2 t-blocks
  const int tg0 = t0 + tb * 16;
  const int rloc0 = b * CH + tb * 16;
  for (int ii = j; ii < 1024; ii += 256) {
    int tr = ii >> 6, k = ii & 63;
    osc64[tr][k] = osc[(size_t)(b * 512 + tg0 + tr) * 128 + k];
  }
  __syncthreads();
  float muv = mu[b * 256 + j], mev = mean[b * 256 + j];
  float acc[16];
#pragma unroll
  for (int tr = 0; tr < 16; ++tr) {
    size_t rg = (size_t)(b * 512 + tg0 + tr);
    xw[(size_t)(rloc0 + tr) * 768 + j] = f2bf(action[rg * 256 + j] * muv + mev);
  }
#pragma unroll
  for (int tr = 0; tr < 16; ++tr) acc[tr] = boscr[j];
  for (int k = 0; k < 64; ++k) {
    float wv = Woscr[k * 256 + j];
#pragma unroll
    for (int tr = 0; tr < 16; ++tr) acc[tr] += osc64[tr][k] * wv;
  }
#pragma unroll
  for (int tr = 0; tr < 16; ++tr) {
    float e = elu_(acc[tr]);
    inp2s[tr][j] = e;
    xw[(size_t)(rloc0 + tr) * 768 + 256 + j] = f2bf(e);
  }
  __syncthreads();
#pragma unroll
  for (int tr = 0; tr < 16; ++tr) acc[tr] = bosci[j];
  for (int k = 0; k < 192; ++k) {
    float wv = Wosci[k * 256 + j];
#pragma unroll
    for (int tr = 0; tr < 16; ++tr) acc[tr] += inp2s[tr][64 + k] * wv;
  }
#pragma unroll
  for (int tr = 0; tr < 16; ++tr)
    xw[(size_t)(rloc0 + tr) * 768 + 512 + j] = f2bf(elu_(acc[tr]));
}

// -------------------- kernel 5: GEMM x @ gru_k + gru_b[0] --------------------
// M=4096 (chunk rows), N=1536, K=768. 128x128 tile, BK=64, 4 waves (2x2 of 64x64).
__global__ __launch_bounds__(256) void gemm_xk(
    const bf16* __restrict__ xw, const bf16* __restrict__ pgk,
    const float* __restrict__ grub, float* __restrict__ xp) {
  __shared__ alignas(16) char sA[16384];  // A [128][64] bf16, row-XOR-swizzled
  __shared__ alignas(16) char sB[16384];  // B [8 kblk][128 n][8 e] bf16
  const int tid = threadIdx.x;
  const int w = tid >> 6, l = tid & 63, lg = l >> 4, li = l & 15;
  const int wr = w >> 1, wc = w & 1;
  const int bm = blockIdx.x / 12, bn = blockIdx.x % 12;
  const int r0 = bm * 128, n0 = bn * 128;

  f32x4 acc[4][4];
#pragma unroll
  for (int a = 0; a < 4; ++a)
#pragma unroll
    for (int b = 0; b < 4; ++b) acc[a][b] = (f32x4){0.f, 0.f, 0.f, 0.f};

  for (int kt = 0; kt < 12; ++kt) {
#pragma unroll
    for (int i = 0; i < 4; ++i) {  // stage A: 16KB
      int c = i * 256 + tid;
      int row = c >> 3, kc = c & 7;
      bf16x8 v = *reinterpret_cast<const bf16x8*>(xw + (size_t)(r0 + row) * 768 + kt * 64 + kc * 8);
      *reinterpret_cast<bf16x8*>(sA + row * 128 + ((kc * 16) ^ ((row & 7) << 4))) = v;
    }
#pragma unroll
    for (int i = 0; i < 4; ++i) {  // stage B: 16KB
      int c = i * 256 + tid;
      int kbl = c >> 7, n = c & 127;
      bf16x8 v = *reinterpret_cast<const bf16x8*>(pgk + ((size_t)(kt * 8 + kbl) * 1536 + n0 + n) * 8);
      *reinterpret_cast<bf16x8*>(sB + kbl * 2048 + n * 16) = v;
    }
    __syncthreads();
#pragma unroll
    for (int kk = 0; kk < 2; ++kk) {
      bf16x8 af[4], bg[4];
#pragma unroll
      for (int fi = 0; fi < 4; ++fi) {
        int row = wr * 64 + fi * 16 + li;
        af[fi] = *reinterpret_cast<const bf16x8*>(sA + row * 128 + ((kk * 64 + lg * 16) ^ ((row & 7) << 4)));
      }
#pragma unroll
      for (int fj = 0; fj < 4; ++fj) {
        int n = wc * 64 + fj * 16 + li;
        bg[fj] = *reinterpret_cast<const bf16x8*>(sB + (kk * 4 + lg) * 2048 + n * 16);
      }
#pragma unroll
      for (int fi = 0; fi < 4; ++fi)
#pragma unroll
        for (int fj = 0; fj < 4; ++fj)
          acc[fi][fj] = mfma16(af[fi], bg[fj], acc[fi][fj]);
    }
    __syncthreads();
  }
  // epilogue: +gru_b[0], write x_proj chunk [tc][b][1536] f32
#pragma unroll
  for (int fj = 0; fj < 4; ++fj) {
    int col = n0 + wc * 64 + fj * 16 + li;
    float gb = grub[col];
#pragma unroll
    for (int fi = 0; fi < 4; ++fi)
#pragma unroll
      for (int i = 0; i < 4; ++i) {
        int r = r0 + wr * 64 + fi * 16 + 4 * lg + i;
        int bidx = r >> 5, tc = r & (CH - 1);  // row = b*CH + tc
        xp[(size_t)(tc * 128 + bidx) * 1536 + col] = acc[fi][fj][i] + gb;
      }
  }
}

// -------------------- kernel 6: GRU scan chunk (CH steps) --------------------
// 8 WGs x 512 thr (8 waves). WG owns 16 batch rows; wave w owns h-cols [w*64,+64)
// for all 3 gates (combine is wave-local, 1 barrier/step). h LDS: [16][512] bf16,
// XOR-swizzled (byte ^ (row&7)<<4), double-buffered.
__global__ __launch_bounds__(512) void gru_scan(
    const bf16* __restrict__ prk, const float* __restrict__ xp,
    const float* __restrict__ grub, float* __restrict__ h_io, float* __restrict__ hm_io,
    const float* __restrict__ Wout, const float* __restrict__ bout,
    float* __restrict__ dout, int first, int last) {
  __shared__ alignas(16) char smem[32768];  // 2 x h_bf16 [16][512]
  const int tid = threadIdx.x;
  const int w = tid >> 6, l = tid & 63, lg = l >> 4, li = l & 15;
  const int b0 = blockIdx.x * 16;

  float hreg[4][4], hmax_[4][4], binit[3][4];
#pragma unroll
  for (int q = 0; q < 4; ++q)
#pragma unroll
    for (int i = 0; i < 4; ++i) {
      int row = 4 * lg + i, col = w * 64 + q * 16 + li;
      hreg[q][i] = h_io[(b0 + row) * 512 + col];
      hmax_[q][i] = first ? -1.0e30f : hm_io[(b0 + row) * 512 + col];
    }
#pragma unroll
  for (int g = 0; g < 3; ++g)
#pragma unroll
    for (int q = 0; q < 4; ++q)
      binit[g][q] = grub[1536 + g * 512 + w * 64 + q * 16 + li];

  for (int ii = tid; ii < 8192; ii += 512) {  // fill h_bf16 buf0 (swizzled)
    int row = ii >> 9, col = ii & 511;
    *reinterpret_cast<bf16*>(smem + row * 1024 + ((col * 2) ^ ((row & 7) << 4))) =
        f2bf(h_io[(b0 + row) * 512 + col]);
  }
  __syncthreads();

  const bf16* prk_lane = prk + l * 8;

  for (int s = 0; s < CH; ++s) {
    const char* hbase = smem + (s & 1) * 16384;
    char* nbase = smem + (((s & 1) ^ 1)) * 16384;
    f32x4 acc[3][4];
#pragma unroll
    for (int g = 0; g < 3; ++g)
#pragma unroll
      for (int q = 0; q < 4; ++q)
        acc[g][q] = (f32x4){binit[g][q], binit[g][q], binit[g][q], binit[g][q]};
    for (int kf = 0; kf < 16; ++kf) {
      bf16x8 a = *reinterpret_cast<const bf16x8*>(
          hbase + li * 1024 + ((kf * 64 + lg * 16) ^ ((li & 7) << 4)));
#pragma unroll
      for (int g = 0; g < 3; ++g)
#pragma unroll
        for (int q = 0; q < 4; ++q) {
          int nf = g * 32 + w * 4 + q;
          bf16x8 bb = *reinterpret_cast<const bf16x8*>(prk_lane + (size_t)(nf * 16 + kf) * 512);
          acc[g][q] = mfma16(a, bb, acc[g][q]);
        }
    }
#pragma unroll
    for (int q = 0; q < 4; ++q)
#pragma unroll
      for (int i = 0; i < 4; ++i) {
        int row = 4 * lg + i, col = w * 64 + q * 16 + li;
        size_t idx = (size_t)(s * 128 + b0 + row) * 1536 + col;
        float z = sigm(xp[idx] + acc[0][q][i]);
        float r = sigm(xp[idx + 512] + acc[1][q][i]);
        float hc = tanh_(xp[idx + 1024] + r * acc[2][q][i]);
        float hn = z * hreg[q][i] + (1.f - z) * hc;
        hmax_[q][i] = fmaxf(hmax_[q][i], hn);
        hreg[q][i] = hn;
        *reinterpret_cast<bf16*>(nbase + row * 1024 + ((col * 2) ^ ((row & 7) << 4))) = f2bf(hn);
      }
    __syncthreads();
  }

#pragma unroll
  for (int q = 0; q < 4; ++q)
#pragma unroll
    for (int i = 0; i < 4; ++i) {
      int row = 4 * lg + i, col = w * 64 + q * 16 + li;
      h_io[(b0 + row) * 512 + col] = hreg[q][i];
      hm_io[(b0 + row) * 512 + col] = hmax_[q][i];
      if (last) dout[128 + (b0 + row) * 512 + col] = hreg[q][i];
    }
  if (last) {
    __syncthreads();
    float* hml = reinterpret_cast<float*>(smem);
#pragma unroll
    for (int q = 0; q < 4; ++q)
#pragma unroll
      for (int i = 0; i < 4; ++i) {
        int row = 4 * lg + i, col = w * 64 + q * 16 + li;
        hml[row * 512 + col] = hmax_[q][i];
      }
    __syncthreads();
    if (tid < 16) {
      float acc = bout[0];
      for (int c2 = 0; c2 < 512; ++c2) acc += hml[tid * 512 + c2] * Wout[c2];
      dout[b0 + tid] = elu_(acc);
    }
  }
}

// -------------------- launch --------------------
extern "C" void kernel_launch(void* const* d_in, const int* in_sizes, int n_in,
                              void* d_out, int out_size, void* d_ws, size_t ws_size,
                              hipStream_t stream) {
  const float* mot = (const float*)d_in[0];
  const float* rob = (const float*)d_in[1];
  const float* action = (const float*)d_in[3];
  const float* osc = (const float*)d_in[4];
  const float* mu = (const float*)d_in[5];
  const float* mean = (const float*)d_in[6];
  const float* state = (const float*)d_in[7];
  const float* Wmot = (const float*)d_in[8];
  const float* bmot = (const float*)d_in[9];
  const float* Wrob = (const float*)d_in[10];
  const float* brob = (const float*)d_in[11];
  const float* Wcomb = (const float*)d_in[12];
  const float* bcomb = (const float*)d_in[13];
  const float* Woscr = (const float*)d_in[14];
  const float* boscr = (const float*)d_in[15];
  const float* Wosci = (const float*)d_in[16];
  const float* bosci = (const float*)d_in[17];
  const float* gk = (const float*)d_in[18];
  const float* grk = (const float*)d_in[19];
  const float* grub = (const float*)d_in[20];
  const float* Wout = (const float*)d_in[21];
  const float* bout = (const float*)d_in[22];
  float* dout = (float*)d_out;

  char* ws = (char*)d_ws;
  float* h = (float*)(ws + OFF_H);
  float* hm = (float*)(ws + OFF_HM);
  bf16* prk = (bf16*)(ws + OFF_PRK);
  bf16* pgk = (bf16*)(ws + OFF_PGK);
  bf16* xw = (bf16*)(ws + OFF_X);
  float* xp = (float*)(ws + OFF_XP);

  prep_h0<<<128, 512, 0, stream>>>(mot, rob, state, Wmot, bmot, Wrob, brob, Wcomb, bcomb, h);
  pack_rk<<<384, 256, 0, stream>>>(grk, prk);
  pack_gk<<<576, 256, 0, stream>>>(gk, pgk);
  for (int c = 0; c < NCHUNK; ++c) {
    int t0 = c * CH;
    build_x<<<256, 256, 0, stream>>>(action, osc, mu, mean, Woscr, boscr, Wosci, bosci, xw, t0);
    gemm_xk<<<384, 256, 0, stream>>>(xw, pgk, grub, xp);
    gru_scan<<<8, 512, 0, stream>>>(prk, xp, grub, h, hm, Wout, bout, dout,
                                    (c == 0) ? 1 : 0, (c == NCHUNK - 1) ? 1 : 0);
  }
}

// Round 4
// 25430.833 us; speedup vs baseline: 1.0725x; 1.0725x over previous
//
#include <hip/hip_runtime.h>
#include <hip/hip_bf16.h>

// CriticRDDPG forward: B=128, T=512, A=256, U_GRU=512
// ALL inputs/outputs are FLOAT32 (per reference). bf16 used only internally
// as MFMA operands. d_out: [out(128) | h_final(128*512)] f32.
// T processed in 16 chunks of CH=32 steps; ws usage ~34.3 MiB.

using bf16 = __hip_bfloat16;
typedef __bf16 bf16x8 __attribute__((ext_vector_type(8)));
typedef float f32x4 __attribute__((ext_vector_type(4)));

#define CH 32
#define NCHUNK 16

__device__ __forceinline__ bf16 f2bf(float f) { return __float2bfloat16(f); }
__device__ __forceinline__ float sigm(float x) { return 1.f / (1.f + __expf(-x)); }
__device__ __forceinline__ float tanh_(float x) {
  float ax = fabsf(x);
  float t = __expf(-2.f * ax);
  float r = (1.f - t) / (1.f + t);
  return copysignf(r, x);
}
__device__ __forceinline__ float elu_(float x) { return x > 0.f ? x : __expf(x) - 1.f; }
__device__ __forceinline__ f32x4 mfma16(bf16x8 a, bf16x8 b, f32x4 c) {
  return __builtin_amdgcn_mfma_f32_16x16x32_bf16(a, b, c, 0, 0, 0);
}

// -------------------- workspace layout (bytes) --------------------
#define OFF_H   0ul                     // h state f32 [128][512]          =   262144
#define OFF_HM  262144ul                // hmax f32 [128][512]             =   262144
#define OFF_PRK 524288ul                // packed gru_rk bf16              =  1572864
#define OFF_PGK 2097152ul               // packed gru_k bf16               =  2359296
#define OFF_X   4456448ul               // x chunk bf16 [128*CH][768]      =  6291456
#define OFF_XP  10747904ul              // x_proj chunk f32 [CH][128][1536]= 25165824
// total = 35913728 (~34.3 MiB)

// -------------------- kernel 1: h0 --------------------
__global__ __launch_bounds__(512) void prep_h0(
    const float* __restrict__ mot, const float* __restrict__ rob,
    const float* __restrict__ state,
    const float* __restrict__ Wmot, const float* __restrict__ bmot,
    const float* __restrict__ Wrob, const float* __restrict__ brob,
    const float* __restrict__ Wcomb, const float* __restrict__ bcomb,
    float* __restrict__ h) {
  __shared__ float inbuf[128];
  __shared__ float msrs[512];
  __shared__ float st[512];
  const int tid = threadIdx.x;
  const int b = blockIdx.x;
  if (tid < 64) inbuf[tid] = mot[b * 64 + tid];
  else if (tid < 128) inbuf[tid] = rob[b * 64 + tid - 64];
  st[tid] = state[b * 512 + tid];
  __syncthreads();
  {
    float acc;
    if (tid < 256) {
      acc = bmot[tid];
      for (int k = 0; k < 64; ++k) acc += inbuf[k] * Wmot[k * 256 + tid];
    } else {
      int jj = tid - 256;
      acc = brob[jj];
      for (int k = 0; k < 64; ++k) acc += inbuf[64 + k] * Wrob[k * 256 + jj];
    }
    msrs[tid] = elu_(acc);
  }
  __syncthreads();
  float acc = bcomb[tid];
  for (int k = 0; k < 512; ++k) acc += msrs[k] * Wcomb[(size_t)k * 512 + tid];
  for (int k = 0; k < 512; ++k) acc += st[k] * Wcomb[(size_t)(512 + k) * 512 + tid];
  h[b * 512 + tid] = elu_(acc);
}

// ---------- kernel 2: pack gru_rk (f32) into MFMA B-fragment order (bf16) ----
// prk frag (nf,kf), lane l, elem e  <-  rk[k][n], n = nf*16+(l&15), k = kf*32+(l>>4)*8+e
__global__ void pack_rk(const float* __restrict__ rk, bf16* __restrict__ prk) {
  int idx = blockIdx.x * 256 + threadIdx.x;  // 96 nf * 16 kf * 64 lanes = 98304
  int nf = idx >> 10, rem = idx & 1023;
  int kf = rem >> 6, l = rem & 63;
  int n = nf * 16 + (l & 15);
  int k0 = kf * 32 + (l >> 4) * 8;
  bf16x8 v;
#pragma unroll
  for (int e = 0; e < 8; ++e)
    v[e] = (__bf16)f2bf(rk[(size_t)(k0 + e) * 1536 + n]);
  *reinterpret_cast<bf16x8*>(prk + (size_t)idx * 8) = v;
}

// ---------- kernel 3: pack gru_k (f32) into k-octet bf16 layout ----------
// pgk[(kblk*1536+n)*8 + e] = gk[kblk*8+e][n]
__global__ void pack_gk(const float* __restrict__ gk, bf16* __restrict__ pgk) {
  int idx = blockIdx.x * 256 + threadIdx.x;  // 96*1536 = 147456
  int kblk = idx / 1536, n = idx % 1536;
  bf16x8 v;
#pragma unroll
  for (int e = 0; e < 8; ++e)
    v[e] = (__bf16)f2bf(gk[(size_t)(kblk * 8 + e) * 1536 + n]);
  *reinterpret_cast<bf16x8*>(pgk + (size_t)idx * 8) = v;
}

// -------------------- kernel 4: build x chunk --------------------
// x rows: rloc = b*CH + (t - t0); cols [act(256) | inp2(256) | inp3(256)], bf16
__global__ __launch_bounds__(256) void build_x(
    const float* __restrict__ action, const float* __restrict__ osc,
    const float* __restrict__ mu, const float* __restrict__ mean,
    const float* __restrict__ Woscr, const float* __restrict__ boscr,
    const float* __restrict__ Wosci, const float* __restrict__ bosci,
    bf16* __restrict__ xw, int t0) {
  __shared__ float osc64[16][64];
  __shared__ float inp2s[16][256];
  const int j = threadIdx.x;
  const int b = blockIdx.x >> 1, tb = blockIdx.x & 1;  // CH/16 = 2 t-blocks
  const int tg0 = t0 + tb * 16;
  const int rloc0 = b * CH + tb * 16;
  for (int ii = j; ii < 1024; ii += 256) {
    int tr = ii >> 6, k = ii & 63;
    osc64[tr][k] = osc[(size_t)(b * 512 + tg0 + tr) * 128 + k];
  }
  __syncthreads();
  float muv = mu[b * 256 + j], mev = mean[b * 256 + j];
  float acc[16];
#pragma unroll
  for (int tr = 0; tr < 16; ++tr) {
    size_t rg = (size_t)(b * 512 + tg0 + tr);
    xw[(size_t)(rloc0 + tr) * 768 + j] = f2bf(action[rg * 256 + j] * muv + mev);
  }
#pragma unroll
  for (int tr = 0; tr < 16; ++tr) acc[tr] = boscr[j];
  for (int k = 0; k < 64; ++k) {
    float wv = Woscr[k * 256 + j];
#pragma unroll
    for (int tr = 0; tr < 16; ++tr) acc[tr] += osc64[tr][k] * wv;
  }
#pragma unroll
  for (int tr = 0; tr < 16; ++tr) {
    float e = elu_(acc[tr]);
    inp2s[tr][j] = e;
    xw[(size_t)(rloc0 + tr) * 768 + 256 + j] = f2bf(e);
  }
  __syncthreads();
#pragma unroll
  for (int tr = 0; tr < 16; ++tr) acc[tr] = bosci[j];
  for (int k = 0; k < 192; ++k) {
    float wv = Wosci[k * 256 + j];
#pragma unroll
    for (int tr = 0; tr < 16; ++tr) acc[tr] += inp2s[tr][64 + k] * wv;
  }
#pragma unroll
  for (int tr = 0; tr < 16; ++tr)
    xw[(size_t)(rloc0 + tr) * 768 + 512 + j] = f2bf(elu_(acc[tr]));
}

// -------------------- kernel 5: GEMM x @ gru_k + gru_b[0] --------------------
// M=4096 (chunk rows), N=1536, K=768. 128x128 tile, BK=64, 4 waves (2x2 of 64x64).
__global__ __launch_bounds__(256) void gemm_xk(
    const bf16* __restrict__ xw, const bf16* __restrict__ pgk,
    const float* __restrict__ grub, float* __restrict__ xp) {
  __shared__ alignas(16) char sA[16384];  // A [128][64] bf16, row-XOR-swizzled
  __shared__ alignas(16) char sB[16384];  // B [8 kblk][128 n][8 e] bf16
  const int tid = threadIdx.x;
  const int w = tid >> 6, l = tid & 63, lg = l >> 4, li = l & 15;
  const int wr = w >> 1, wc = w & 1;
  const int bm = blockIdx.x / 12, bn = blockIdx.x % 12;
  const int r0 = bm * 128, n0 = bn * 128;

  f32x4 acc[4][4];
#pragma unroll
  for (int a = 0; a < 4; ++a)
#pragma unroll
    for (int b = 0; b < 4; ++b) acc[a][b] = (f32x4){0.f, 0.f, 0.f, 0.f};

  for (int kt = 0; kt < 12; ++kt) {
#pragma unroll
    for (int i = 0; i < 4; ++i) {  // stage A: 16KB
      int c = i * 256 + tid;
      int row = c >> 3, kc = c & 7;
      bf16x8 v = *reinterpret_cast<const bf16x8*>(xw + (size_t)(r0 + row) * 768 + kt * 64 + kc * 8);
      *reinterpret_cast<bf16x8*>(sA + row * 128 + ((kc * 16) ^ ((row & 7) << 4))) = v;
    }
#pragma unroll
    for (int i = 0; i < 4; ++i) {  // stage B: 16KB
      int c = i * 256 + tid;
      int kbl = c >> 7, n = c & 127;
      bf16x8 v = *reinterpret_cast<const bf16x8*>(pgk + ((size_t)(kt * 8 + kbl) * 1536 + n0 + n) * 8);
      *reinterpret_cast<bf16x8*>(sB + kbl * 2048 + n * 16) = v;
    }
    __syncthreads();
#pragma unroll
    for (int kk = 0; kk < 2; ++kk) {
      bf16x8 af[4], bg[4];
#pragma unroll
      for (int fi = 0; fi < 4; ++fi) {
        int row = wr * 64 + fi * 16 + li;
        af[fi] = *reinterpret_cast<const bf16x8*>(sA + row * 128 + ((kk * 64 + lg * 16) ^ ((row & 7) << 4)));
      }
#pragma unroll
      for (int fj = 0; fj < 4; ++fj) {
        int n = wc * 64 + fj * 16 + li;
        bg[fj] = *reinterpret_cast<const bf16x8*>(sB + (kk * 4 + lg) * 2048 + n * 16);
      }
#pragma unroll
      for (int fi = 0; fi < 4; ++fi)
#pragma unroll
        for (int fj = 0; fj < 4; ++fj)
          acc[fi][fj] = mfma16(af[fi], bg[fj], acc[fi][fj]);
    }
    __syncthreads();
  }
  // epilogue: +gru_b[0], write x_proj chunk [tc][b][1536] f32
#pragma unroll
  for (int fj = 0; fj < 4; ++fj) {
    int col = n0 + wc * 64 + fj * 16 + li;
    float gb = grub[col];
#pragma unroll
    for (int fi = 0; fi < 4; ++fi)
#pragma unroll
      for (int i = 0; i < 4; ++i) {
        int r = r0 + wr * 64 + fi * 16 + 4 * lg + i;
        int bidx = r >> 5, tc = r & (CH - 1);  // row = b*CH + tc
        xp[(size_t)(tc * 128 + bidx) * 1536 + col] = acc[fi][fj][i] + gb;
      }
  }
}

// -------------------- kernel 6: GRU scan chunk (CH steps) --------------------
// 8 WGs x 512 thr (8 waves). WG owns 16 batch rows; wave w owns h-cols [w*64,+64)
// for all 3 gates (combine is wave-local, 1 barrier/step). h LDS: [16][512] bf16,
// XOR-swizzled, double-buffered. xp for step s is PREFETCHED into registers at
// the top of step s (48 f32/thread) and drains under the MFMA phase.
__global__ __launch_bounds__(512) void gru_scan(
    const bf16* __restrict__ prk, const float* __restrict__ xp,
    const float* __restrict__ grub, float* __restrict__ h_io, float* __restrict__ hm_io,
    const float* __restrict__ Wout, const float* __restrict__ bout,
    float* __restrict__ dout, int first, int last) {
  __shared__ alignas(16) char smem[32768];  // 2 x h_bf16 [16][512]
  const int tid = threadIdx.x;
  const int w = tid >> 6, l = tid & 63, lg = l >> 4, li = l & 15;
  const int b0 = blockIdx.x * 16;

  float hreg[4][4], hmax_[4][4], binit[3][4];
#pragma unroll
  for (int q = 0; q < 4; ++q)
#pragma unroll
    for (int i = 0; i < 4; ++i) {
      int row = 4 * lg + i, col = w * 64 + q * 16 + li;
      hreg[q][i] = h_io[(b0 + row) * 512 + col];
      hmax_[q][i] = first ? -1.0e30f : hm_io[(b0 + row) * 512 + col];
    }
#pragma unroll
  for (int g = 0; g < 3; ++g)
#pragma unroll
    for (int q = 0; q < 4; ++q)
      binit[g][q] = grub[1536 + g * 512 + w * 64 + q * 16 + li];

  for (int ii = tid; ii < 8192; ii += 512) {  // fill h_bf16 buf0 (swizzled)
    int row = ii >> 9, col = ii & 511;
    *reinterpret_cast<bf16*>(smem + row * 1024 + ((col * 2) ^ ((row & 7) << 4))) =
        f2bf(h_io[(b0 + row) * 512 + col]);
  }
  __syncthreads();

  const bf16* prk_lane = prk + l * 8;
  // per-thread xp base: rows b0+4lg.., col base w*64+li
  const float* xp_lane = xp + (size_t)b0 * 1536 + (size_t)(4 * lg) * 1536 + w * 64 + li;

  for (int s = 0; s < CH; ++s) {
    const char* hbase = smem + (s & 1) * 16384;
    char* nbase = smem + (((s & 1) ^ 1)) * 16384;

    // ---- prefetch xp[s] into registers (issued before MFMA phase) ----
    float xr[3][4][4];
    const float* xps = xp_lane + (size_t)s * 128 * 1536;
#pragma unroll
    for (int g = 0; g < 3; ++g)
#pragma unroll
      for (int q = 0; q < 4; ++q)
#pragma unroll
        for (int i = 0; i < 4; ++i)
          xr[g][q][i] = xps[i * 1536 + g * 512 + q * 16];
    __builtin_amdgcn_sched_barrier(0);  // pin loads above the MFMA phase

    f32x4 acc[3][4];
#pragma unroll
    for (int g = 0; g < 3; ++g)
#pragma unroll
      for (int q = 0; q < 4; ++q)
        acc[g][q] = (f32x4){binit[g][q], binit[g][q], binit[g][q], binit[g][q]};
    for (int kf = 0; kf < 16; ++kf) {
      bf16x8 a = *reinterpret_cast<const bf16x8*>(
          hbase + li * 1024 + ((kf * 64 + lg * 16) ^ ((li & 7) << 4)));
#pragma unroll
      for (int g = 0; g < 3; ++g)
#pragma unroll
        for (int q = 0; q < 4; ++q) {
          int nf = g * 32 + w * 4 + q;
          bf16x8 bb = *reinterpret_cast<const bf16x8*>(prk_lane + (size_t)(nf * 16 + kf) * 512);
          acc[g][q] = mfma16(a, bb, acc[g][q]);
        }
    }
#pragma unroll
    for (int q = 0; q < 4; ++q)
#pragma unroll
      for (int i = 0; i < 4; ++i) {
        int row = 4 * lg + i, col = w * 64 + q * 16 + li;
        float z = sigm(xr[0][q][i] + acc[0][q][i]);
        float r = sigm(xr[1][q][i] + acc[1][q][i]);
        float hc = tanh_(xr[2][q][i] + r * acc[2][q][i]);
        float hn = z * hreg[q][i] + (1.f - z) * hc;
        hmax_[q][i] = fmaxf(hmax_[q][i], hn);
        hreg[q][i] = hn;
        *reinterpret_cast<bf16*>(nbase + row * 1024 + ((col * 2) ^ ((row & 7) << 4))) = f2bf(hn);
      }
    __syncthreads();
  }

#pragma unroll
  for (int q = 0; q < 4; ++q)
#pragma unroll
    for (int i = 0; i < 4; ++i) {
      int row = 4 * lg + i, col = w * 64 + q * 16 + li;
      h_io[(b0 + row) * 512 + col] = hreg[q][i];
      hm_io[(b0 + row) * 512 + col] = hmax_[q][i];
      if (last) dout[128 + (b0 + row) * 512 + col] = hreg[q][i];
    }
  if (last) {
    __syncthreads();
    float* hml = reinterpret_cast<float*>(smem);
#pragma unroll
    for (int q = 0; q < 4; ++q)
#pragma unroll
      for (int i = 0; i < 4; ++i) {
        int row = 4 * lg + i, col = w * 64 + q * 16 + li;
        hml[row * 512 + col] = hmax_[q][i];
      }
    __syncthreads();
    if (tid < 16) {
      float acc = bout[0];
      for (int c2 = 0; c2 < 512; ++c2) acc += hml[tid * 512 + c2] * Wout[c2];
      dout[b0 + tid] = elu_(acc);
    }
  }
}

// -------------------- launch --------------------
extern "C" void kernel_launch(void* const* d_in, const int* in_sizes, int n_in,
                              void* d_out, int out_size, void* d_ws, size_t ws_size,
                              hipStream_t stream) {
  const float* mot = (const float*)d_in[0];
  const float* rob = (const float*)d_in[1];
  const float* action = (const float*)d_in[3];
  const float* osc = (const float*)d_in[4];
  const float* mu = (const float*)d_in[5];
  const float* mean = (const float*)d_in[6];
  const float* state = (const float*)d_in[7];
  const float* Wmot = (const float*)d_in[8];
  const float* bmot = (const float*)d_in[9];
  const float* Wrob = (const float*)d_in[10];
  const float* brob = (const float*)d_in[11];
  const float* Wcomb = (const float*)d_in[12];
  const float* bcomb = (const float*)d_in[13];
  const float* Woscr = (const float*)d_in[14];
  const float* boscr = (const float*)d_in[15];
  const float* Wosci = (const float*)d_in[16];
  const float* bosci = (const float*)d_in[17];
  const float* gk = (const float*)d_in[18];
  const float* grk = (const float*)d_in[19];
  const float* grub = (const float*)d_in[20];
  const float* Wout = (const float*)d_in[21];
  const float* bout = (const float*)d_in[22];
  float* dout = (float*)d_out;

  char* ws = (char*)d_ws;
  float* h = (float*)(ws + OFF_H);
  float* hm = (float*)(ws + OFF_HM);
  bf16* prk = (bf16*)(ws + OFF_PRK);
  bf16* pgk = (bf16*)(ws + OFF_PGK);
  bf16* xw = (bf16*)(ws + OFF_X);
  float* xp = (float*)(ws + OFF_XP);

  prep_h0<<<128, 512, 0, stream>>>(mot, rob, state, Wmot, bmot, Wrob, brob, Wcomb, bcomb, h);
  pack_rk<<<384, 256, 0, stream>>>(grk, prk);
  pack_gk<<<576, 256, 0, stream>>>(gk, pgk);
  for (int c = 0; c < NCHUNK; ++c) {
    int t0 = c * CH;
    build_x<<<256, 256, 0, stream>>>(action, osc, mu, mean, Woscr, boscr, Wosci, bosci, xw, t0);
    gemm_xk<<<384, 256, 0, stream>>>(xw, pgk, grub, xp);
    gru_scan<<<8, 512, 0, stream>>>(prk, xp, grub, h, hm, Wout, bout, dout,
                                    (c == 0) ? 1 : 0, (c == NCHUNK - 1) ? 1 : 0);
  }
}

// Round 5
// 5589.980 us; speedup vs baseline: 4.8794x; 4.5494x over previous
//
#include <hip/hip_runtime.h>
#include <hip/hip_bf16.h>

// CriticRDDPG forward: B=128, T=512, A=256, U_GRU=512
// ALL inputs/outputs are FLOAT32 (per reference). bf16 used internally as
// MFMA operands. d_out: [out(128) | h_final(128*512)] f32.
// T processed in 16 chunks of CH=32 steps.
//
// GRU scan: 64 WGs = 8 batch-groups x 8 col-groups (64 h-cols each).
// Cross-WG h exchange per step via global hx (double-buffered) + per-bg
// monotonic counter with device-scope release/acquire atomics.

using bf16 = __hip_bfloat16;
typedef __bf16 bf16x8 __attribute__((ext_vector_type(8)));
typedef float f32x4 __attribute__((ext_vector_type(4)));

#define CH 32
#define NCHUNK 16

__device__ __forceinline__ bf16 f2bf(float f) { return __float2bfloat16(f); }
__device__ __forceinline__ float sigm(float x) { return 1.f / (1.f + __expf(-x)); }
__device__ __forceinline__ float tanh_(float x) {
  float ax = fabsf(x);
  float t = __expf(-2.f * ax);
  float r = (1.f - t) / (1.f + t);
  return copysignf(r, x);
}
__device__ __forceinline__ float elu_(float x) { return x > 0.f ? x : __expf(x) - 1.f; }
__device__ __forceinline__ f32x4 mfma16(bf16x8 a, bf16x8 b, f32x4 c) {
  return __builtin_amdgcn_mfma_f32_16x16x32_bf16(a, b, c, 0, 0, 0);
}

// -------------------- workspace layout (bytes) --------------------
#define OFF_H   0ul                     // h state f32 [128][512]          =   262144
#define OFF_HM  262144ul                // hmax f32 [128][512]             =   262144
#define OFF_PRK 524288ul                // packed gru_rk bf16              =  1572864
#define OFF_PGK 2097152ul               // packed gru_k bf16               =  2359296
#define OFF_X   4456448ul               // x chunk bf16 [128*CH][768]      =  6291456
#define OFF_XP  10747904ul              // x_proj chunk f32 [CH][128][1536]= 25165824
#define OFF_HX  35913728ul              // hx bf16 [2][128][512]           =   262144
#define OFF_CNT 36175872ul              // counters 8 x 64B                =     1024
// total ~34.6 MiB

// -------------------- kernel 1: h0 --------------------
__global__ __launch_bounds__(512) void prep_h0(
    const float* __restrict__ mot, const float* __restrict__ rob,
    const float* __restrict__ state,
    const float* __restrict__ Wmot, const float* __restrict__ bmot,
    const float* __restrict__ Wrob, const float* __restrict__ brob,
    const float* __restrict__ Wcomb, const float* __restrict__ bcomb,
    float* __restrict__ h) {
  __shared__ float inbuf[128];
  __shared__ float msrs[512];
  __shared__ float st[512];
  const int tid = threadIdx.x;
  const int b = blockIdx.x;
  if (tid < 64) inbuf[tid] = mot[b * 64 + tid];
  else if (tid < 128) inbuf[tid] = rob[b * 64 + tid - 64];
  st[tid] = state[b * 512 + tid];
  __syncthreads();
  {
    float acc;
    if (tid < 256) {
      acc = bmot[tid];
      for (int k = 0; k < 64; ++k) acc += inbuf[k] * Wmot[k * 256 + tid];
    } else {
      int jj = tid - 256;
      acc = brob[jj];
      for (int k = 0; k < 64; ++k) acc += inbuf[64 + k] * Wrob[k * 256 + jj];
    }
    msrs[tid] = elu_(acc);
  }
  __syncthreads();
  float acc = bcomb[tid];
  for (int k = 0; k < 512; ++k) acc += msrs[k] * Wcomb[(size_t)k * 512 + tid];
  for (int k = 0; k < 512; ++k) acc += st[k] * Wcomb[(size_t)(512 + k) * 512 + tid];
  h[b * 512 + tid] = elu_(acc);
}

// ---------- kernel 2: pack gru_rk (f32) into MFMA B-fragment order (bf16) ----
// prk frag (nf,kf), lane l, elem e  <-  rk[k][n], n = nf*16+(l&15), k = kf*32+(l>>4)*8+e
__global__ void pack_rk(const float* __restrict__ rk, bf16* __restrict__ prk) {
  int idx = blockIdx.x * 256 + threadIdx.x;  // 96 nf * 16 kf * 64 lanes = 98304
  int nf = idx >> 10, rem = idx & 1023;
  int kf = rem >> 6, l = rem & 63;
  int n = nf * 16 + (l & 15);
  int k0 = kf * 32 + (l >> 4) * 8;
  bf16x8 v;
#pragma unroll
  for (int e = 0; e < 8; ++e)
    v[e] = (__bf16)f2bf(rk[(size_t)(k0 + e) * 1536 + n]);
  *reinterpret_cast<bf16x8*>(prk + (size_t)idx * 8) = v;
}

// ---------- kernel 3: pack gru_k (f32) into k-octet bf16 layout ----------
// pgk[(kblk*1536+n)*8 + e] = gk[kblk*8+e][n]
__global__ void pack_gk(const float* __restrict__ gk, bf16* __restrict__ pgk) {
  int idx = blockIdx.x * 256 + threadIdx.x;  // 96*1536 = 147456
  int kblk = idx / 1536, n = idx % 1536;
  bf16x8 v;
#pragma unroll
  for (int e = 0; e < 8; ++e)
    v[e] = (__bf16)f2bf(gk[(size_t)(kblk * 8 + e) * 1536 + n]);
  *reinterpret_cast<bf16x8*>(pgk + (size_t)idx * 8) = v;
}

// -------------------- kernel 4: build x chunk --------------------
__global__ __launch_bounds__(256) void build_x(
    const float* __restrict__ action, const float* __restrict__ osc,
    const float* __restrict__ mu, const float* __restrict__ mean,
    const float* __restrict__ Woscr, const float* __restrict__ boscr,
    const float* __restrict__ Wosci, const float* __restrict__ bosci,
    bf16* __restrict__ xw, int t0) {
  __shared__ float osc64[16][64];
  __shared__ float inp2s[16][256];
  const int j = threadIdx.x;
  const int b = blockIdx.x >> 1, tb = blockIdx.x & 1;
  const int tg0 = t0 + tb * 16;
  const int rloc0 = b * CH + tb * 16;
  for (int ii = j; ii < 1024; ii += 256) {
    int tr = ii >> 6, k = ii & 63;
    osc64[tr][k] = osc[(size_t)(b * 512 + tg0 + tr) * 128 + k];
  }
  __syncthreads();
  float muv = mu[b * 256 + j], mev = mean[b * 256 + j];
  float acc[16];
#pragma unroll
  for (int tr = 0; tr < 16; ++tr) {
    size_t rg = (size_t)(b * 512 + tg0 + tr);
    xw[(size_t)(rloc0 + tr) * 768 + j] = f2bf(action[rg * 256 + j] * muv + mev);
  }
#pragma unroll
  for (int tr = 0; tr < 16; ++tr) acc[tr] = boscr[j];
  for (int k = 0; k < 64; ++k) {
    float wv = Woscr[k * 256 + j];
#pragma unroll
    for (int tr = 0; tr < 16; ++tr) acc[tr] += osc64[tr][k] * wv;
  }
#pragma unroll
  for (int tr = 0; tr < 16; ++tr) {
    float e = elu_(acc[tr]);
    inp2s[tr][j] = e;
    xw[(size_t)(rloc0 + tr) * 768 + 256 + j] = f2bf(e);
  }
  __syncthreads();
#pragma unroll
  for (int tr = 0; tr < 16; ++tr) acc[tr] = bosci[j];
  for (int k = 0; k < 192; ++k) {
    float wv = Wosci[k * 256 + j];
#pragma unroll
    for (int tr = 0; tr < 16; ++tr) acc[tr] += inp2s[tr][64 + k] * wv;
  }
#pragma unroll
  for (int tr = 0; tr < 16; ++tr)
    xw[(size_t)(rloc0 + tr) * 768 + 512 + j] = f2bf(elu_(acc[tr]));
}

// -------------------- kernel 5: GEMM x @ gru_k + gru_b[0] --------------------
__global__ __launch_bounds__(256) void gemm_xk(
    const bf16* __restrict__ xw, const bf16* __restrict__ pgk,
    const float* __restrict__ grub, float* __restrict__ xp) {
  __shared__ alignas(16) char sA[16384];
  __shared__ alignas(16) char sB[16384];
  const int tid = threadIdx.x;
  const int w = tid >> 6, l = tid & 63, lg = l >> 4, li = l & 15;
  const int wr = w >> 1, wc = w & 1;
  const int bm = blockIdx.x / 12, bn = blockIdx.x % 12;
  const int r0 = bm * 128, n0 = bn * 128;

  f32x4 acc[4][4];
#pragma unroll
  for (int a = 0; a < 4; ++a)
#pragma unroll
    for (int b = 0; b < 4; ++b) acc[a][b] = (f32x4){0.f, 0.f, 0.f, 0.f};

  for (int kt = 0; kt < 12; ++kt) {
#pragma unroll
    for (int i = 0; i < 4; ++i) {
      int c = i * 256 + tid;
      int row = c >> 3, kc = c & 7;
      bf16x8 v = *reinterpret_cast<const bf16x8*>(xw + (size_t)(r0 + row) * 768 + kt * 64 + kc * 8);
      *reinterpret_cast<bf16x8*>(sA + row * 128 + ((kc * 16) ^ ((row & 7) << 4))) = v;
    }
#pragma unroll
    for (int i = 0; i < 4; ++i) {
      int c = i * 256 + tid;
      int kbl = c >> 7, n = c & 127;
      bf16x8 v = *reinterpret_cast<const bf16x8*>(pgk + ((size_t)(kt * 8 + kbl) * 1536 + n0 + n) * 8);
      *reinterpret_cast<bf16x8*>(sB + kbl * 2048 + n * 16) = v;
    }
    __syncthreads();
#pragma unroll
    for (int kk = 0; kk < 2; ++kk) {
      bf16x8 af[4], bg[4];
#pragma unroll
      for (int fi = 0; fi < 4; ++fi) {
        int row = wr * 64 + fi * 16 + li;
        af[fi] = *reinterpret_cast<const bf16x8*>(sA + row * 128 + ((kk * 64 + lg * 16) ^ ((row & 7) << 4)));
      }
#pragma unroll
      for (int fj = 0; fj < 4; ++fj) {
        int n = wc * 64 + fj * 16 + li;
        bg[fj] = *reinterpret_cast<const bf16x8*>(sB + (kk * 4 + lg) * 2048 + n * 16);
      }
#pragma unroll
      for (int fi = 0; fi < 4; ++fi)
#pragma unroll
        for (int fj = 0; fj < 4; ++fj)
          acc[fi][fj] = mfma16(af[fi], bg[fj], acc[fi][fj]);
    }
    __syncthreads();
  }
#pragma unroll
  for (int fj = 0; fj < 4; ++fj) {
    int col = n0 + wc * 64 + fj * 16 + li;
    float gb = grub[col];
#pragma unroll
    for (int fi = 0; fi < 4; ++fi)
#pragma unroll
      for (int i = 0; i < 4; ++i) {
        int r = r0 + wr * 64 + fi * 16 + 4 * lg + i;
        int bidx = r >> 5, tc = r & (CH - 1);
        xp[(size_t)(tc * 128 + bidx) * 1536 + col] = acc[fi][fj][i] + gb;
      }
  }
}

// -------------------- kernel 6: GRU scan chunk, 64-WG version --------------------
// Grid 64: WG (bg, cg) owns rows [bg*16,+16) x h-cols [cg*64,+64).
// 256 thr = 4 waves; wave w owns cols [cg*64+w*16,+16) for all 3 gates
// (nf_z = cg*4+w, nf_r = 32+nf_z, nf_h = 64+nf_z).
// Per step: MFMA over full h (LDS) -> gates -> write bf16 slice to hx[s&1]
// -> release counter -> acquire-spin for all 8 col-WGs -> reload LDS h.
__global__ __launch_bounds__(256, 1) void gru_scan(
    const bf16* __restrict__ prk, const float* __restrict__ xp,
    const float* __restrict__ grub, float* __restrict__ h_io,
    float* __restrict__ hm_io, bf16* __restrict__ hx,
    unsigned int* __restrict__ cnt, float* __restrict__ dout,
    int step_base, int first, int last) {
  __shared__ alignas(16) char sH[16384];  // h bf16 [16][512], XOR-swizzled
  const int tid = threadIdx.x;
  const int w = tid >> 6, l = tid & 63, lg = l >> 4, li = l & 15;
  const int bg = blockIdx.x >> 3, cg = blockIdx.x & 7;
  const int b0 = bg * 16;
  const int wc = cg * 64 + w * 16;          // wave's col base
  const int nfz = (cg << 2) + w;            // z-gate fragment index

  float hreg[4], hmax_[4], binit[3];
#pragma unroll
  for (int i = 0; i < 4; ++i) {
    int row = 4 * lg + i, col = wc + li;
    hreg[i] = h_io[(b0 + row) * 512 + col];
    hmax_[i] = first ? -1.0e30f : hm_io[(b0 + row) * 512 + col];
  }
#pragma unroll
  for (int g = 0; g < 3; ++g) binit[g] = grub[1536 + g * 512 + wc + li];

  // seed LDS h from h_io (f32 -> bf16, swizzled)
#pragma unroll
  for (int j = 0; j < 4; ++j) {
    int cc = j * 256 + tid;       // 1024 octets
    int row = cc >> 6, c8 = cc & 63;
    const float* src = h_io + (size_t)(b0 + row) * 512 + c8 * 8;
    bf16x8 v;
#pragma unroll
    for (int e = 0; e < 8; ++e) v[e] = (__bf16)f2bf(src[e]);
    *reinterpret_cast<bf16x8*>(sH + row * 1024 + ((c8 * 16) ^ ((row & 7) << 4))) = v;
  }
  __syncthreads();

  const bf16* prk_lane = prk + l * 8;
  const float* xp_lane = xp + (size_t)(b0 + 4 * lg) * 1536 + wc + li;
  unsigned int* mycnt = cnt + bg * 16;

  for (int s = 0; s < CH; ++s) {
    // prefetch xp[s] (12 scalar f32 loads)
    float xr[3][4];
    const float* xps = xp_lane + (size_t)s * 128 * 1536;
#pragma unroll
    for (int g = 0; g < 3; ++g)
#pragma unroll
      for (int i = 0; i < 4; ++i)
        xr[g][i] = xps[i * 1536 + g * 512];
    __builtin_amdgcn_sched_barrier(0);

    f32x4 acc[3];
#pragma unroll
    for (int g = 0; g < 3; ++g)
      acc[g] = (f32x4){binit[g], binit[g], binit[g], binit[g]};
#pragma unroll
    for (int kf = 0; kf < 16; ++kf) {
      bf16x8 a = *reinterpret_cast<const bf16x8*>(
          sH + li * 1024 + ((kf * 64 + lg * 16) ^ ((li & 7) << 4)));
      bf16x8 bz = *reinterpret_cast<const bf16x8*>(prk_lane + (size_t)(nfz * 16 + kf) * 512);
      bf16x8 br = *reinterpret_cast<const bf16x8*>(prk_lane + (size_t)((32 + nfz) * 16 + kf) * 512);
      bf16x8 bh = *reinterpret_cast<const bf16x8*>(prk_lane + (size_t)((64 + nfz) * 16 + kf) * 512);
      acc[0] = mfma16(a, bz, acc[0]);
      acc[1] = mfma16(a, br, acc[1]);
      acc[2] = mfma16(a, bh, acc[2]);
    }

    // gates + write own hx slice (bf16)
    bf16* hxb = hx + (size_t)(s & 1) * 65536;
#pragma unroll
    for (int i = 0; i < 4; ++i) {
      int row = 4 * lg + i, col = wc + li;
      float z = sigm(xr[0][i] + acc[0][i]);
      float r = sigm(xr[1][i] + acc[1][i]);
      float hc = tanh_(xr[2][i] + r * acc[2][i]);
      float hn = z * hreg[i] + (1.f - z) * hc;
      hmax_[i] = fmaxf(hmax_[i], hn);
      hreg[i] = hn;
      hxb[(size_t)(b0 + row) * 512 + col] = f2bf(hn);
    }
    __syncthreads();  // all waves' MFMA-reads done + hx stores drained (vmcnt0 before barrier)
    if (tid == 0)
      __hip_atomic_fetch_add(mycnt, 1u, __ATOMIC_RELEASE, __HIP_MEMORY_SCOPE_AGENT);
    unsigned int tgt = 8u * (unsigned int)(step_base + s + 1);
    int guard = 0;
    while (__hip_atomic_load(mycnt, __ATOMIC_ACQUIRE, __HIP_MEMORY_SCOPE_AGENT) < tgt) {
      __builtin_amdgcn_s_sleep(2);
      if (++guard > (1 << 22)) break;  // bail out instead of hanging
    }
    // reload full h row-block from hx[s&1] into LDS
#pragma unroll
    for (int j = 0; j < 4; ++j) {
      int cc = j * 256 + tid;
      int row = cc >> 6, c8 = cc & 63;
      bf16x8 v = *reinterpret_cast<const bf16x8*>(hxb + (size_t)(b0 + row) * 512 + c8 * 8);
      *reinterpret_cast<bf16x8*>(sH + row * 1024 + ((c8 * 16) ^ ((row & 7) << 4))) = v;
    }
    __syncthreads();
  }

  // chunk epilogue: persist own f32 slice
#pragma unroll
  for (int i = 0; i < 4; ++i) {
    int row = 4 * lg + i, col = wc + li;
    h_io[(b0 + row) * 512 + col] = hreg[i];
    hm_io[(b0 + row) * 512 + col] = hmax_[i];
    if (last) dout[128 + (b0 + row) * 512 + col] = hreg[i];
  }
}

// -------------------- kernel 7: out = elu(hmax @ W_out + b_out) ------------
__global__ __launch_bounds__(64) void final_out(
    const float* __restrict__ hm, const float* __restrict__ Wout,
    const float* __restrict__ bout, float* __restrict__ dout) {
  const int b = blockIdx.x, l = threadIdx.x;
  float a = 0.f;
  for (int c = l; c < 512; c += 64) a += hm[b * 512 + c] * Wout[c];
#pragma unroll
  for (int off = 32; off; off >>= 1) a += __shfl_xor(a, off, 64);
  if (l == 0) dout[b] = elu_(a + bout[0]);
}

// -------------------- launch --------------------
extern "C" void kernel_launch(void* const* d_in, const int* in_sizes, int n_in,
                              void* d_out, int out_size, void* d_ws, size_t ws_size,
                              hipStream_t stream) {
  const float* mot = (const float*)d_in[0];
  const float* rob = (const float*)d_in[1];
  const float* action = (const float*)d_in[3];
  const float* osc = (const float*)d_in[4];
  const float* mu = (const float*)d_in[5];
  const float* mean = (const float*)d_in[6];
  const float* state = (const float*)d_in[7];
  const float* Wmot = (const float*)d_in[8];
  const float* bmot = (const float*)d_in[9];
  const float* Wrob = (const float*)d_in[10];
  const float* brob = (const float*)d_in[11];
  const float* Wcomb = (const float*)d_in[12];
  const float* bcomb = (const float*)d_in[13];
  const float* Woscr = (const float*)d_in[14];
  const float* boscr = (const float*)d_in[15];
  const float* Wosci = (const float*)d_in[16];
  const float* bosci = (const float*)d_in[17];
  const float* gk = (const float*)d_in[18];
  const float* grk = (const float*)d_in[19];
  const float* grub = (const float*)d_in[20];
  const float* Wout = (const float*)d_in[21];
  const float* bout = (const float*)d_in[22];
  float* dout = (float*)d_out;

  char* ws = (char*)d_ws;
  float* h = (float*)(ws + OFF_H);
  float* hm = (float*)(ws + OFF_HM);
  bf16* prk = (bf16*)(ws + OFF_PRK);
  bf16* pgk = (bf16*)(ws + OFF_PGK);
  bf16* xw = (bf16*)(ws + OFF_X);
  float* xp = (float*)(ws + OFF_XP);
  bf16* hx = (bf16*)(ws + OFF_HX);
  unsigned int* cnt = (unsigned int*)(ws + OFF_CNT);

  hipMemsetAsync(ws + OFF_CNT, 0, 1024, stream);
  prep_h0<<<128, 512, 0, stream>>>(mot, rob, state, Wmot, bmot, Wrob, brob, Wcomb, bcomb, h);
  pack_rk<<<384, 256, 0, stream>>>(grk, prk);
  pack_gk<<<576, 256, 0, stream>>>(gk, pgk);
  for (int c = 0; c < NCHUNK; ++c) {
    int t0 = c * CH;
    build_x<<<256, 256, 0, stream>>>(action, osc, mu, mean, Woscr, boscr, Wosci, bosci, xw, t0);
    gemm_xk<<<384, 256, 0, stream>>>(xw, pgk, grub, xp);
    gru_scan<<<64, 256, 0, stream>>>(prk, xp, grub, h, hm, hx, cnt, dout,
                                     c * CH, (c == 0) ? 1 : 0, (c == NCHUNK - 1) ? 1 : 0);
  }
  final_out<<<128, 64, 0, stream>>>(hm, Wout, bout, dout);
}

// Round 6
// 4825.842 us; speedup vs baseline: 5.6520x; 1.1583x over previous
//
#include <hip/hip_runtime.h>
#include <hip/hip_bf16.h>

// CriticRDDPG forward: B=128, T=512, A=256, U_GRU=512
// ALL inputs/outputs are FLOAT32 (per reference). bf16 used internally as
// MFMA operands. d_out: [out(128) | h_final(128*512)] f32.
// T processed in 16 chunks of CH=32 steps.
//
// GRU scan: 64 WGs = 8 batch-groups x 8 col-groups (64 h-cols each).
// bg = blockIdx&7 so all 8 WGs of a batch-group land on ONE XCD (round-robin
// dispatch) -> hx exchange + counter stay XCD-local. B-fragments (gru_rk)
// live in 192 VGPRs per lane (immune to sync cache-ops). Cross-WG h exchange
// per step via global hx (double-buffered) + per-bg monotonic counter with
// device-scope release/acquire atomics.

using bf16 = __hip_bfloat16;
typedef __bf16 bf16x8 __attribute__((ext_vector_type(8)));
typedef float f32x4 __attribute__((ext_vector_type(4)));

#define CH 32
#define NCHUNK 16

__device__ __forceinline__ bf16 f2bf(float f) { return __float2bfloat16(f); }
__device__ __forceinline__ float sigm(float x) { return 1.f / (1.f + __expf(-x)); }
__device__ __forceinline__ float tanh_(float x) {
  float ax = fabsf(x);
  float t = __expf(-2.f * ax);
  float r = (1.f - t) / (1.f + t);
  return copysignf(r, x);
}
__device__ __forceinline__ float elu_(float x) { return x > 0.f ? x : __expf(x) - 1.f; }
__device__ __forceinline__ f32x4 mfma16(bf16x8 a, bf16x8 b, f32x4 c) {
  return __builtin_amdgcn_mfma_f32_16x16x32_bf16(a, b, c, 0, 0, 0);
}

// -------------------- workspace layout (bytes) --------------------
#define OFF_H   0ul                     // h state f32 [128][512]          =   262144
#define OFF_HM  262144ul                // hmax f32 [128][512]             =   262144
#define OFF_PRK 524288ul                // packed gru_rk bf16              =  1572864
#define OFF_PGK 2097152ul               // packed gru_k bf16               =  2359296
#define OFF_X   4456448ul               // x chunk bf16 [128*CH][768]      =  6291456
#define OFF_XP  10747904ul              // x_proj chunk f32 [CH][128][1536]= 25165824
#define OFF_HX  35913728ul              // hx bf16 [2][128][512]           =   262144
#define OFF_CNT 36175872ul              // counters 8 x 64B                =     1024
// total ~34.6 MiB

// -------------------- kernel 1: h0 --------------------
__global__ __launch_bounds__(512) void prep_h0(
    const float* __restrict__ mot, const float* __restrict__ rob,
    const float* __restrict__ state,
    const float* __restrict__ Wmot, const float* __restrict__ bmot,
    const float* __restrict__ Wrob, const float* __restrict__ brob,
    const float* __restrict__ Wcomb, const float* __restrict__ bcomb,
    float* __restrict__ h) {
  __shared__ float inbuf[128];
  __shared__ float msrs[512];
  __shared__ float st[512];
  const int tid = threadIdx.x;
  const int b = blockIdx.x;
  if (tid < 64) inbuf[tid] = mot[b * 64 + tid];
  else if (tid < 128) inbuf[tid] = rob[b * 64 + tid - 64];
  st[tid] = state[b * 512 + tid];
  __syncthreads();
  {
    float acc;
    if (tid < 256) {
      acc = bmot[tid];
      for (int k = 0; k < 64; ++k) acc += inbuf[k] * Wmot[k * 256 + tid];
    } else {
      int jj = tid - 256;
      acc = brob[jj];
      for (int k = 0; k < 64; ++k) acc += inbuf[64 + k] * Wrob[k * 256 + jj];
    }
    msrs[tid] = elu_(acc);
  }
  __syncthreads();
  float acc = bcomb[tid];
  for (int k = 0; k < 512; ++k) acc += msrs[k] * Wcomb[(size_t)k * 512 + tid];
  for (int k = 0; k < 512; ++k) acc += st[k] * Wcomb[(size_t)(512 + k) * 512 + tid];
  h[b * 512 + tid] = elu_(acc);
}

// ---------- kernel 2: pack gru_rk (f32) into MFMA B-fragment order (bf16) ----
// prk frag (nf,kf), lane l, elem e  <-  rk[k][n], n = nf*16+(l&15), k = kf*32+(l>>4)*8+e
__global__ void pack_rk(const float* __restrict__ rk, bf16* __restrict__ prk) {
  int idx = blockIdx.x * 256 + threadIdx.x;  // 96 nf * 16 kf * 64 lanes = 98304
  int nf = idx >> 10, rem = idx & 1023;
  int kf = rem >> 6, l = rem & 63;
  int n = nf * 16 + (l & 15);
  int k0 = kf * 32 + (l >> 4) * 8;
  bf16x8 v;
#pragma unroll
  for (int e = 0; e < 8; ++e)
    v[e] = (__bf16)f2bf(rk[(size_t)(k0 + e) * 1536 + n]);
  *reinterpret_cast<bf16x8*>(prk + (size_t)idx * 8) = v;
}

// ---------- kernel 3: pack gru_k (f32) into k-octet bf16 layout ----------
// pgk[(kblk*1536+n)*8 + e] = gk[kblk*8+e][n]
__global__ void pack_gk(const float* __restrict__ gk, bf16* __restrict__ pgk) {
  int idx = blockIdx.x * 256 + threadIdx.x;  // 96*1536 = 147456
  int kblk = idx / 1536, n = idx % 1536;
  bf16x8 v;
#pragma unroll
  for (int e = 0; e < 8; ++e)
    v[e] = (__bf16)f2bf(gk[(size_t)(kblk * 8 + e) * 1536 + n]);
  *reinterpret_cast<bf16x8*>(pgk + (size_t)idx * 8) = v;
}

// -------------------- kernel 4: build x chunk --------------------
__global__ __launch_bounds__(256) void build_x(
    const float* __restrict__ action, const float* __restrict__ osc,
    const float* __restrict__ mu, const float* __restrict__ mean,
    const float* __restrict__ Woscr, const float* __restrict__ boscr,
    const float* __restrict__ Wosci, const float* __restrict__ bosci,
    bf16* __restrict__ xw, int t0) {
  __shared__ float osc64[16][64];
  __shared__ float inp2s[16][256];
  const int j = threadIdx.x;
  const int b = blockIdx.x >> 1, tb = blockIdx.x & 1;
  const int tg0 = t0 + tb * 16;
  const int rloc0 = b * CH + tb * 16;
  for (int ii = j; ii < 1024; ii += 256) {
    int tr = ii >> 6, k = ii & 63;
    osc64[tr][k] = osc[(size_t)(b * 512 + tg0 + tr) * 128 + k];
  }
  __syncthreads();
  float muv = mu[b * 256 + j], mev = mean[b * 256 + j];
  float acc[16];
#pragma unroll
  for (int tr = 0; tr < 16; ++tr) {
    size_t rg = (size_t)(b * 512 + tg0 + tr);
    xw[(size_t)(rloc0 + tr) * 768 + j] = f2bf(action[rg * 256 + j] * muv + mev);
  }
#pragma unroll
  for (int tr = 0; tr < 16; ++tr) acc[tr] = boscr[j];
  for (int k = 0; k < 64; ++k) {
    float wv = Woscr[k * 256 + j];
#pragma unroll
    for (int tr = 0; tr < 16; ++tr) acc[tr] += osc64[tr][k] * wv;
  }
#pragma unroll
  for (int tr = 0; tr < 16; ++tr) {
    float e = elu_(acc[tr]);
    inp2s[tr][j] = e;
    xw[(size_t)(rloc0 + tr) * 768 + 256 + j] = f2bf(e);
  }
  __syncthreads();
#pragma unroll
  for (int tr = 0; tr < 16; ++tr) acc[tr] = bosci[j];
  for (int k = 0; k < 192; ++k) {
    float wv = Wosci[k * 256 + j];
#pragma unroll
    for (int tr = 0; tr < 16; ++tr) acc[tr] += inp2s[tr][64 + k] * wv;
  }
#pragma unroll
  for (int tr = 0; tr < 16; ++tr)
    xw[(size_t)(rloc0 + tr) * 768 + 512 + j] = f2bf(elu_(acc[tr]));
}

// -------------------- kernel 5: GEMM x @ gru_k + gru_b[0] --------------------
__global__ __launch_bounds__(256) void gemm_xk(
    const bf16* __restrict__ xw, const bf16* __restrict__ pgk,
    const float* __restrict__ grub, float* __restrict__ xp) {
  __shared__ alignas(16) char sA[16384];
  __shared__ alignas(16) char sB[16384];
  const int tid = threadIdx.x;
  const int w = tid >> 6, l = tid & 63, lg = l >> 4, li = l & 15;
  const int wr = w >> 1, wc = w & 1;
  const int bm = blockIdx.x / 12, bn = blockIdx.x % 12;
  const int r0 = bm * 128, n0 = bn * 128;

  f32x4 acc[4][4];
#pragma unroll
  for (int a = 0; a < 4; ++a)
#pragma unroll
    for (int b = 0; b < 4; ++b) acc[a][b] = (f32x4){0.f, 0.f, 0.f, 0.f};

  for (int kt = 0; kt < 12; ++kt) {
#pragma unroll
    for (int i = 0; i < 4; ++i) {
      int c = i * 256 + tid;
      int row = c >> 3, kc = c & 7;
      bf16x8 v = *reinterpret_cast<const bf16x8*>(xw + (size_t)(r0 + row) * 768 + kt * 64 + kc * 8);
      *reinterpret_cast<bf16x8*>(sA + row * 128 + ((kc * 16) ^ ((row & 7) << 4))) = v;
    }
#pragma unroll
    for (int i = 0; i < 4; ++i) {
      int c = i * 256 + tid;
      int kbl = c >> 7, n = c & 127;
      bf16x8 v = *reinterpret_cast<const bf16x8*>(pgk + ((size_t)(kt * 8 + kbl) * 1536 + n0 + n) * 8);
      *reinterpret_cast<bf16x8*>(sB + kbl * 2048 + n * 16) = v;
    }
    __syncthreads();
#pragma unroll
    for (int kk = 0; kk < 2; ++kk) {
      bf16x8 af[4], bg[4];
#pragma unroll
      for (int fi = 0; fi < 4; ++fi) {
        int row = wr * 64 + fi * 16 + li;
        af[fi] = *reinterpret_cast<const bf16x8*>(sA + row * 128 + ((kk * 64 + lg * 16) ^ ((row & 7) << 4)));
      }
#pragma unroll
      for (int fj = 0; fj < 4; ++fj) {
        int n = wc * 64 + fj * 16 + li;
        bg[fj] = *reinterpret_cast<const bf16x8*>(sB + (kk * 4 + lg) * 2048 + n * 16);
      }
#pragma unroll
      for (int fi = 0; fi < 4; ++fi)
#pragma unroll
        for (int fj = 0; fj < 4; ++fj)
          acc[fi][fj] = mfma16(af[fi], bg[fj], acc[fi][fj]);
    }
    __syncthreads();
  }
#pragma unroll
  for (int fj = 0; fj < 4; ++fj) {
    int col = n0 + wc * 64 + fj * 16 + li;
    float gb = grub[col];
#pragma unroll
    for (int fi = 0; fi < 4; ++fi)
#pragma unroll
      for (int i = 0; i < 4; ++i) {
        int r = r0 + wr * 64 + fi * 16 + 4 * lg + i;
        int bidx = r >> 5, tc = r & (CH - 1);
        xp[(size_t)(tc * 128 + bidx) * 1536 + col] = acc[fi][fj][i] + gb;
      }
  }
}

// -------------------- kernel 6: GRU scan chunk, 64-WG, reg-B version --------
// Grid 64: WG (bg=blockIdx&7, cg=blockIdx>>3) owns rows [bg*16,+16) x cols
// [cg*64,+64). 4 waves; wave w owns cols [cg*64+w*16,+16) for all 3 gates
// (nf_z = cg*4+w, nf_r = 32+nf_z, nf_h = 64+nf_z). B-fragments preloaded to
// 192 VGPRs/lane. Per step: MFMA(A from LDS, B regs) -> gates -> hx slice
// store -> release counter -> acquire-spin (8 releases/step) -> reload LDS h.
__global__ __launch_bounds__(256, 1) void gru_scan(
    const bf16* __restrict__ prk, const float* __restrict__ xp,
    const float* __restrict__ grub, float* __restrict__ h_io,
    float* __restrict__ hm_io, bf16* __restrict__ hx,
    unsigned int* __restrict__ cnt, float* __restrict__ dout,
    int step_base, int first, int last) {
  __shared__ alignas(16) char sH[16384];  // h bf16 [16][512], XOR-swizzled
  const int tid = threadIdx.x;
  const int w = tid >> 6, l = tid & 63, lg = l >> 4, li = l & 15;
  const int bg = blockIdx.x & 7, cg = blockIdx.x >> 3;  // bg co-located per XCD
  const int b0 = bg * 16;
  const int wc = cg * 64 + w * 16;
  const int nfz = (cg << 2) + w;

  // ---- preload B fragments into registers (z,r,h) x 16 kf ----
  const bf16* prk_lane = prk + l * 8;
  bf16x8 bz[16], br[16], bh[16];
#pragma unroll
  for (int kf = 0; kf < 16; ++kf) {
    bz[kf] = *reinterpret_cast<const bf16x8*>(prk_lane + (size_t)(nfz * 16 + kf) * 512);
    br[kf] = *reinterpret_cast<const bf16x8*>(prk_lane + (size_t)((32 + nfz) * 16 + kf) * 512);
    bh[kf] = *reinterpret_cast<const bf16x8*>(prk_lane + (size_t)((64 + nfz) * 16 + kf) * 512);
  }

  float hreg[4], hmax_[4], binit[3];
#pragma unroll
  for (int i = 0; i < 4; ++i) {
    int row = 4 * lg + i, col = wc + li;
    hreg[i] = h_io[(b0 + row) * 512 + col];
    hmax_[i] = first ? -1.0e30f : hm_io[(b0 + row) * 512 + col];
  }
#pragma unroll
  for (int g = 0; g < 3; ++g) binit[g] = grub[1536 + g * 512 + wc + li];

  // seed LDS h from h_io (f32 -> bf16, swizzled)
#pragma unroll
  for (int j = 0; j < 4; ++j) {
    int cc = j * 256 + tid;  // 1024 octets
    int row = cc >> 6, c8 = cc & 63;
    const float* src = h_io + (size_t)(b0 + row) * 512 + c8 * 8;
    bf16x8 v;
#pragma unroll
    for (int e = 0; e < 8; ++e) v[e] = (__bf16)f2bf(src[e]);
    *reinterpret_cast<bf16x8*>(sH + row * 1024 + ((c8 * 16) ^ ((row & 7) << 4))) = v;
  }
  __syncthreads();

  const float* xp_lane = xp + (size_t)(b0 + 4 * lg) * 1536 + wc + li;
  unsigned int* mycnt = cnt + bg * 16;

  for (int s = 0; s < CH; ++s) {
    // prefetch xp[s] (12 scalar f32 loads) — drain under MFMA phase
    float xr[3][4];
    const float* xps = xp_lane + (size_t)s * 128 * 1536;
#pragma unroll
    for (int g = 0; g < 3; ++g)
#pragma unroll
      for (int i = 0; i < 4; ++i)
        xr[g][i] = xps[i * 1536 + g * 512];
    __builtin_amdgcn_sched_barrier(0);

    f32x4 acc[3];
#pragma unroll
    for (int g = 0; g < 3; ++g)
      acc[g] = (f32x4){binit[g], binit[g], binit[g], binit[g]};
#pragma unroll
    for (int kf = 0; kf < 16; ++kf) {
      bf16x8 a = *reinterpret_cast<const bf16x8*>(
          sH + li * 1024 + ((kf * 64 + lg * 16) ^ ((li & 7) << 4)));
      acc[0] = mfma16(a, bz[kf], acc[0]);
      acc[1] = mfma16(a, br[kf], acc[1]);
      acc[2] = mfma16(a, bh[kf], acc[2]);
    }

    // gates + write own hx slice (bf16)
    bf16* hxb = hx + (size_t)(s & 1) * 65536;
#pragma unroll
    for (int i = 0; i < 4; ++i) {
      int row = 4 * lg + i, col = wc + li;
      float z = sigm(xr[0][i] + acc[0][i]);
      float r = sigm(xr[1][i] + acc[1][i]);
      float hc = tanh_(xr[2][i] + r * acc[2][i]);
      float hn = z * hreg[i] + (1.f - z) * hc;
      hmax_[i] = fmaxf(hmax_[i], hn);
      hreg[i] = hn;
      hxb[(size_t)(b0 + row) * 512 + col] = f2bf(hn);
    }
    __syncthreads();  // drains all waves' hx stores (vmcnt0) + sH reads done
    if (tid == 0)
      __hip_atomic_fetch_add(mycnt, 1u, __ATOMIC_RELEASE, __HIP_MEMORY_SCOPE_AGENT);
    unsigned int tgt = 8u * (unsigned int)(step_base + s + 1);
    int guard = 0;
    while (__hip_atomic_load(mycnt, __ATOMIC_ACQUIRE, __HIP_MEMORY_SCOPE_AGENT) < tgt) {
      __builtin_amdgcn_s_sleep(1);
      if (++guard > (1 << 23)) break;  // bail out instead of hanging
    }
    // reload full h row-block from hx[s&1] into LDS
#pragma unroll
    for (int j = 0; j < 4; ++j) {
      int cc = j * 256 + tid;
      int row = cc >> 6, c8 = cc & 63;
      bf16x8 v = *reinterpret_cast<const bf16x8*>(hxb + (size_t)(b0 + row) * 512 + c8 * 8);
      *reinterpret_cast<bf16x8*>(sH + row * 1024 + ((c8 * 16) ^ ((row & 7) << 4))) = v;
    }
    __syncthreads();
  }

  // chunk epilogue: persist own f32 slice
#pragma unroll
  for (int i = 0; i < 4; ++i) {
    int row = 4 * lg + i, col = wc + li;
    h_io[(b0 + row) * 512 + col] = hreg[i];
    hm_io[(b0 + row) * 512 + col] = hmax_[i];
    if (last) dout[128 + (b0 + row) * 512 + col] = hreg[i];
  }
}

// -------------------- kernel 7: out = elu(hmax @ W_out + b_out) ------------
__global__ __launch_bounds__(64) void final_out(
    const float* __restrict__ hm, const float* __restrict__ Wout,
    const float* __restrict__ bout, float* __restrict__ dout) {
  const int b = blockIdx.x, l = threadIdx.x;
  float a = 0.f;
  for (int c = l; c < 512; c += 64) a += hm[b * 512 + c] * Wout[c];
#pragma unroll
  for (int off = 32; off; off >>= 1) a += __shfl_xor(a, off, 64);
  if (l == 0) dout[b] = elu_(a + bout[0]);
}

// -------------------- launch --------------------
extern "C" void kernel_launch(void* const* d_in, const int* in_sizes, int n_in,
                              void* d_out, int out_size, void* d_ws, size_t ws_size,
                              hipStream_t stream) {
  const float* mot = (const float*)d_in[0];
  const float* rob = (const float*)d_in[1];
  const float* action = (const float*)d_in[3];
  const float* osc = (const float*)d_in[4];
  const float* mu = (const float*)d_in[5];
  const float* mean = (const float*)d_in[6];
  const float* state = (const float*)d_in[7];
  const float* Wmot = (const float*)d_in[8];
  const float* bmot = (const float*)d_in[9];
  const float* Wrob = (const float*)d_in[10];
  const float* brob = (const float*)d_in[11];
  const float* Wcomb = (const float*)d_in[12];
  const float* bcomb = (const float*)d_in[13];
  const float* Woscr = (const float*)d_in[14];
  const float* boscr = (const float*)d_in[15];
  const float* Wosci = (const float*)d_in[16];
  const float* bosci = (const float*)d_in[17];
  const float* gk = (const float*)d_in[18];
  const float* grk = (const float*)d_in[19];
  const float* grub = (const float*)d_in[20];
  const float* Wout = (const float*)d_in[21];
  const float* bout = (const float*)d_in[22];
  float* dout = (float*)d_out;

  char* ws = (char*)d_ws;
  float* h = (float*)(ws + OFF_H);
  float* hm = (float*)(ws + OFF_HM);
  bf16* prk = (bf16*)(ws + OFF_PRK);
  bf16* pgk = (bf16*)(ws + OFF_PGK);
  bf16* xw = (bf16*)(ws + OFF_X);
  float* xp = (float*)(ws + OFF_XP);
  bf16* hx = (bf16*)(ws + OFF_HX);
  unsigned int* cnt = (unsigned int*)(ws + OFF_CNT);

  hipMemsetAsync(ws + OFF_CNT, 0, 1024, stream);
  prep_h0<<<128, 512, 0, stream>>>(mot, rob, state, Wmot, bmot, Wrob, brob, Wcomb, bcomb, h);
  pack_rk<<<384, 256, 0, stream>>>(grk, prk);
  pack_gk<<<576, 256, 0, stream>>>(gk, pgk);
  for (int c = 0; c < NCHUNK; ++c) {
    int t0 = c * CH;
    build_x<<<256, 256, 0, stream>>>(action, osc, mu, mean, Woscr, boscr, Wosci, bosci, xw, t0);
    gemm_xk<<<384, 256, 0, stream>>>(xw, pgk, grub, xp);
    gru_scan<<<64, 256, 0, stream>>>(prk, xp, grub, h, hm, hx, cnt, dout,
                                     c * CH, (c == 0) ? 1 : 0, (c == NCHUNK - 1) ? 1 : 0);
  }
  final_out<<<128, 64, 0, stream>>>(hm, Wout, bout, dout);
}